// Round 1
// baseline (571.728 us; speedup 1.0000x reference)
//
#include <hip/hip_runtime.h>
#include <math.h>

#define CDIM 256
#define NE   1024
#define HW   4096            // 64*64
#define NB   16
#define ZQ_SIZE (NB*CDIM*HW) // 16777216

#define BM 32                // tokens per block
#define BN 256               // codes per j-tile
#define BK 16                // k-chunk staged in LDS
#define JT (NE/BN)           // 4
#define KT (CDIM/BK)         // 16

// squared value with contraction blocked (replicates numpy's mul-then-add)
__device__ __forceinline__ float sq_nofma(float v) {
    float v2 = v * v;
    asm volatile("" : "+v"(v2));
    return v2;
}

// numpy pairwise_sum of 256 squared elements:
// split 128+128; each 128-block uses 8 accumulators then pairwise combine.
template <typename F>
__device__ __forceinline__ float pairwise256_sq(F get) {
    float total = 0.0f;
    #pragma unroll
    for (int h = 0; h < 2; ++h) {
        float r[8];
        #pragma unroll
        for (int j = 0; j < 8; ++j) r[j] = sq_nofma(get(h * 128 + j));
        #pragma unroll
        for (int i = 8; i < 128; i += 8) {
            #pragma unroll
            for (int j = 0; j < 8; ++j) r[j] += sq_nofma(get(h * 128 + i + j));
        }
        float s = ((r[0] + r[1]) + (r[2] + r[3])) + ((r[4] + r[5]) + (r[6] + r[7]));
        total = (h == 0) ? s : (total + s);
    }
    return total;
}

// ||emb_j||^2 for all 1024 codes -> ws
__global__ __launch_bounds__(256) void ee_kernel(const float* __restrict__ emb,
                                                 float* __restrict__ ee) {
    int j = blockIdx.x * 256 + threadIdx.x;
    const float* row = emb + (size_t)j * CDIM;
    ee[j] = pairwise256_sq([&](int i) { return row[i]; });
}

__global__ __launch_bounds__(256, 3) void vq_kernel(const float* __restrict__ z,
                                                    const float* __restrict__ emb,
                                                    const float* __restrict__ ee,
                                                    float* __restrict__ out) {
    __shared__ float zs[CDIM][BM];   // 32 KB, z tile (k-major)
    __shared__ float es[BK][BN];     // 16 KB, emb chunk (k-major)
    __shared__ float ees[BN];        // ||e||^2 for current j-tile
    __shared__ float zzs[BM];        // ||z||^2 per token
    __shared__ float red_d[4][BM];
    __shared__ int   red_j[4][BM];
    __shared__ int   bestj_s[BM];

    const int tid = threadIdx.x;
    const int b   = blockIdx.x >> 7;          // 128 hw-tiles per batch
    const int hw0 = (blockIdx.x & 127) << 5;  // *BM
    const int ti  = tid & 7;
    const int tj  = tid >> 3;
    const int tm0 = ti << 2;   // 4 tokens per thread
    const int jc0 = tj << 3;   // 8 codes per thread within tile

    // ---- stage z tile: zs[c][t] ----
    {
        const float* zb = z + (size_t)b * CDIM * HW + hw0;
        #pragma unroll
        for (int r = 0; r < 8; ++r) {
            int f4 = (r << 8) + tid;      // 0..2047
            int c  = f4 >> 3;             // 8 float4 per row of 32
            int t4 = (f4 & 7) << 2;
            float4 v = *reinterpret_cast<const float4*>(zb + (size_t)c * HW + t4);
            *reinterpret_cast<float4*>(&zs[c][t4]) = v;
        }
    }
    __syncthreads();

    // ---- ||z||^2 per token, numpy pairwise order ----
    if (tid < BM) {
        zzs[tid] = pairwise256_sq([&](int i) { return zs[i][tid]; });
    }
    __syncthreads();

    float bd[4];
    int   bj[4];
    #pragma unroll
    for (int i = 0; i < 4; ++i) { bd[i] = INFINITY; bj[i] = NE; }

    for (int jt = 0; jt < JT; ++jt) {
        const int j0 = jt * BN;
        float acc[4][8];
        #pragma unroll
        for (int i = 0; i < 4; ++i)
            #pragma unroll
            for (int jj = 0; jj < 8; ++jj) acc[i][jj] = 0.0f;

        for (int kt = 0; kt < KT; ++kt) {
            __syncthreads();
            // stage es[k][j] (transpose emb rows)
            #pragma unroll
            for (int r = 0; r < 4; ++r) {
                int f4 = (r << 8) + tid;     // 0..1023
                int jj = f4 >> 2;            // 4 float4 per 16-wide row
                int c4 = (f4 & 3) << 2;
                float4 v = *reinterpret_cast<const float4*>(
                    emb + (size_t)(j0 + jj) * CDIM + kt * BK + c4);
                es[c4 + 0][jj] = v.x;
                es[c4 + 1][jj] = v.y;
                es[c4 + 2][jj] = v.z;
                es[c4 + 3][jj] = v.w;
            }
            if (kt == 0 && tid < BN) ees[tid] = ee[j0 + tid];
            __syncthreads();

            #pragma unroll
            for (int k = 0; k < BK; ++k) {
                float4 av  = *reinterpret_cast<const float4*>(&zs[kt * BK + k][tm0]);
                float4 bv0 = *reinterpret_cast<const float4*>(&es[k][jc0]);
                float4 bv1 = *reinterpret_cast<const float4*>(&es[k][jc0 + 4]);
                float a0 = av.x, a1 = av.y, a2 = av.z, a3 = av.w;
                float bb[8] = {bv0.x, bv0.y, bv0.z, bv0.w, bv1.x, bv1.y, bv1.z, bv1.w};
                #pragma unroll
                for (int jj = 0; jj < 8; ++jj) {
                    acc[0][jj] = fmaf(a0, bb[jj], acc[0][jj]);
                    acc[1][jj] = fmaf(a1, bb[jj], acc[1][jj]);
                    acc[2][jj] = fmaf(a2, bb[jj], acc[2][jj]);
                    acc[3][jj] = fmaf(a3, bb[jj], acc[3][jj]);
                }
            }
        }

        // epilogue: d = (zz + ee) - 2*dot, running argmin (ascending j, strict <)
        #pragma unroll
        for (int i = 0; i < 4; ++i) {
            float zzv = zzs[tm0 + i];
            #pragma unroll
            for (int jj = 0; jj < 8; ++jj) {
                float t1 = zzv + ees[jc0 + jj];
                float d  = t1 - 2.0f * acc[i][jj];
                if (d < bd[i]) { bd[i] = d; bj[i] = j0 + jc0 + jj; }
            }
        }
    }

    // ---- reduce across the 32 code-columns sharing each token ----
    // in-wave: lanes l, l^8, l^16, l^32 share the same 4 tokens
    #pragma unroll
    for (int off = 8; off <= 32; off <<= 1) {
        #pragma unroll
        for (int i = 0; i < 4; ++i) {
            float od = __shfl_xor(bd[i], off);
            int   oj = __shfl_xor(bj[i], off);
            if (od < bd[i] || (od == bd[i] && oj < bj[i])) { bd[i] = od; bj[i] = oj; }
        }
    }
    {
        const int lane = tid & 63;
        const int w    = tid >> 6;
        if (lane < 8) {
            #pragma unroll
            for (int i = 0; i < 4; ++i) {
                red_d[w][lane * 4 + i] = bd[i];
                red_j[w][lane * 4 + i] = bj[i];
            }
        }
    }
    __syncthreads();

    if (tid < BM) {
        float d = red_d[0][tid];
        int   j = red_j[0][tid];
        #pragma unroll
        for (int w2 = 1; w2 < 4; ++w2) {
            float od = red_d[w2][tid];
            int   oj = red_j[w2][tid];
            if (od < d || (od == d && oj < j)) { d = od; j = oj; }
        }
        bestj_s[tid] = j;
        out[(size_t)ZQ_SIZE + (size_t)b * HW + hw0 + tid] = (float)j;
    }
    __syncthreads();

    // ---- write z_q in NCHW: out[b][c][hw0+t] = emb[bestj][c] ----
    {
        const int t  = tid & 31;
        const int c0 = tid >> 5;   // 8 channel groups
        const int jb = bestj_s[t];
        const float* er = emb + (size_t)jb * CDIM;
        float* ob = out + (size_t)b * CDIM * HW + hw0 + t;
        #pragma unroll
        for (int c = c0; c < CDIM; c += 8) {
            ob[(size_t)c * HW] = er[c];
        }
    }
}

extern "C" void kernel_launch(void* const* d_in, const int* in_sizes, int n_in,
                              void* d_out, int out_size, void* d_ws, size_t ws_size,
                              hipStream_t stream) {
    const float* z   = (const float*)d_in[0];
    const float* emb = (const float*)d_in[1];
    float* ee  = (float*)d_ws;   // 1024 floats
    float* out = (float*)d_out;

    ee_kernel<<<dim3(NE / 256), dim3(256), 0, stream>>>(emb, ee);
    vq_kernel<<<dim3((NB * HW) / BM), dim3(256), 0, stream>>>(z, emb, ee, out);
}